// Round 2
// baseline (864.884 us; speedup 1.0000x reference)
//
#include <hip/hip_runtime.h>
#include <hip/hip_bf16.h>

// Problem constants (fixed by setup_inputs)
#define BB   32      // batch
#define TT   4096    // seq len
#define CTXD 1024    // encoder hidden (K of the big GEMM)
#define HH   256     // attention hidden (N of the big GEMM)
#define DH   512     // decoder hidden
#define BT   64      // t-rows per block
#define NTILES (TT/BT)  // 64 tiles per batch
#define BK   32      // K-chunk staged per iteration
#define NKT  (CTXD/BK)  // 32 iterations
#define LDA  1032    // As full-row stride in bf16 elems: 2064 B = 516 dw == 4 mod 32 banks
#define LDU  40      // Us row stride in bf16 elems: 80 B = 20 dw == 20 mod 32 banks
// dynamic LDS: As 64*1032*2=132096 + Us 256*40*2=20480 + epart 1024 + pbuf 256 = 153856 B
#define SMEM_BYTES (BT*LDA*2 + HH*LDU*2 + 4*BT*4 + BT*4)

typedef __attribute__((ext_vector_type(8))) short bf16x8;
typedef __attribute__((ext_vector_type(4))) float f32x4;

static __device__ __forceinline__ unsigned short f2bf(float f) {
    unsigned int u = __float_as_uint(f);
    u += 0x7FFF + ((u >> 16) & 1);   // round-to-nearest-even
    return (unsigned short)(u >> 16);
}
static __device__ __forceinline__ unsigned pack2(float x, float y) {
    return (unsigned)f2bf(x) | ((unsigned)f2bf(y) << 16);
}
static __device__ __forceinline__ float bf2f(unsigned short u) {
    return __uint_as_float((unsigned)u << 16);
}

// ---- prep: U_w fp32 -> bf16 (row-major [H][CTX]) ----
__global__ void uconv_kernel(const float* __restrict__ Uw, unsigned short* __restrict__ Ub) {
    int idx = blockIdx.x * blockDim.x + threadIdx.x;  // 65536 threads, 4 elems each
    float4 u4 = ((const float4*)Uw)[idx];
    ushort4 o;
    o.x = f2bf(u4.x); o.y = f2bf(u4.y); o.z = f2bf(u4.z); o.w = f2bf(u4.w);
    ((ushort4*)Ub)[idx] = o;
}

// ---- prep: bias[b,h] = prev[b,:]·W_w[h,:] + W_b[h] + U_b[h] (full fp32) ----
__global__ void bias_kernel(const float* __restrict__ prev, const float* __restrict__ Ww,
                            const float* __restrict__ Wb, const float* __restrict__ Ubias,
                            float* __restrict__ bias) {
    __shared__ float ps[DH];
    int b = blockIdx.x, h = threadIdx.x;
    if (h < DH / 4) ((float4*)ps)[h] = ((const float4*)(prev + (size_t)b * DH))[h];
    __syncthreads();
    float acc = Wb[h] + Ubias[h];
    const float4* wr = (const float4*)(Ww + (size_t)h * DH);
    #pragma unroll 4
    for (int d = 0; d < DH / 4; ++d) {
        float4 w4 = wr[d];
        float4 p4 = ((const float4*)ps)[d];
        acc += w4.x * p4.x + w4.y * p4.y + w4.z * p4.z + w4.w * p4.w;
    }
    bias[b * HH + h] = acc;
}

// ---- main: single-pass over enc. Persistent full-row bf16 A-tile in LDS:
//      GEMM stages enc once (fp32->bf16, SW-pipelined), phase-3 reads LDS. ----
__global__ __launch_bounds__(256, 1)
void attn_main(const float* __restrict__ enc, const unsigned short* __restrict__ Ub,
               const float* __restrict__ bias, const float* __restrict__ v,
               float* __restrict__ partO, float* __restrict__ partM,
               float* __restrict__ partL) {
    extern __shared__ __align__(16) char smem[];
    unsigned short* As = (unsigned short*)smem;                    // 64 x LDA
    unsigned short* Us = (unsigned short*)(smem + BT * LDA * 2);   // 256 x LDU
    float* epart = (float*)(smem + BT * LDA * 2 + HH * LDU * 2);   // [4][64]
    float* pbuf  = epart + 4 * BT;                                  // [64]

    const int tid  = threadIdx.x;
    const int lane = tid & 63;
    const int w    = tid >> 6;         // wave 0..3 -> N columns [64w, 64w+64)
    const int quad = lane >> 4;
    const int l15  = lane & 15;
    const int b    = blockIdx.x & 31;
    const int tile = blockIdx.x >> 5;
    const int t0   = tile * BT;
    const int pi   = b * NTILES + tile;

    // staging thread map: 4 threads per row, 8 elems (one 16B bf16 granule) each
    const int srow = tid >> 2;     // 0..63
    const int sg   = tid & 3;      // granule 0..3 within 32-col chunk
    const float*          gA = enc + ((size_t)b * TT + t0 + srow) * CTXD + sg * 8;
    const unsigned short* gU = Ub + (size_t)srow * CTXD + sg * 8;

    f32x4 acc[4][4];
    #pragma unroll
    for (int mi = 0; mi < 4; ++mi)
        #pragma unroll
        for (int ni = 0; ni < 4; ++ni) acc[mi][ni] = (f32x4){0.f, 0.f, 0.f, 0.f};

    // prologue: issue kt=0 loads
    float4 ca0 = *(const float4*)(gA);
    float4 ca1 = *(const float4*)(gA + 4);
    uint4  cu0 = *(const uint4*)(gU);
    uint4  cu1 = *(const uint4*)(gU + (size_t)64 * CTXD);
    uint4  cu2 = *(const uint4*)(gU + (size_t)128 * CTXD);
    uint4  cu3 = *(const uint4*)(gU + (size_t)192 * CTXD);

    for (int kt = 0; kt < NKT; ++kt) {
        // issue next chunk's loads BEFORE this chunk's store/compute (SW pipeline)
        int ktn = (kt + 1 < NKT) ? kt + 1 : kt;
        float4 na0 = *(const float4*)(gA + ktn * BK);
        float4 na1 = *(const float4*)(gA + ktn * BK + 4);
        uint4  nu0 = *(const uint4*)(gU + ktn * BK);
        uint4  nu1 = *(const uint4*)(gU + (size_t)64 * CTXD + ktn * BK);
        uint4  nu2 = *(const uint4*)(gU + (size_t)128 * CTXD + ktn * BK);
        uint4  nu3 = *(const uint4*)(gU + (size_t)192 * CTXD + ktn * BK);

        __syncthreads();   // previous iter's Us reads complete before overwrite
        // store current chunk to LDS (A converted fp32->bf16; persists across kt)
        uint4 pa;
        pa.x = pack2(ca0.x, ca0.y); pa.y = pack2(ca0.z, ca0.w);
        pa.z = pack2(ca1.x, ca1.y); pa.w = pack2(ca1.z, ca1.w);
        *(uint4*)&As[srow * LDA + kt * BK + sg * 8] = pa;
        *(uint4*)&Us[(srow      ) * LDU + sg * 8] = cu0;
        *(uint4*)&Us[(srow +  64) * LDU + sg * 8] = cu1;
        *(uint4*)&Us[(srow + 128) * LDU + sg * 8] = cu2;
        *(uint4*)&Us[(srow + 192) * LDU + sg * 8] = cu3;
        __syncthreads();

        // fragments + MFMA (one 16x16x32 K-step per kt)
        bf16x8 af[4], bfr[4];
        #pragma unroll
        for (int mi = 0; mi < 4; ++mi)
            af[mi] = *(const bf16x8*)&As[(mi * 16 + l15) * LDA + kt * BK + quad * 8];
        #pragma unroll
        for (int ni = 0; ni < 4; ++ni)
            bfr[ni] = *(const bf16x8*)&Us[(w * 64 + ni * 16 + l15) * LDU + quad * 8];
        #pragma unroll
        for (int mi = 0; mi < 4; ++mi)
            #pragma unroll
            for (int ni = 0; ni < 4; ++ni)
                acc[mi][ni] = __builtin_amdgcn_mfma_f32_16x16x32_bf16(af[mi], bfr[ni], acc[mi][ni], 0, 0, 0);

        ca0 = na0; ca1 = na1; cu0 = nu0; cu1 = nu1; cu2 = nu2; cu3 = nu3;
    }

    // epilogue: energy[t] = sum_h relu(S[t,h] + bias[b,h]) * v[h]
    float vv[4], bb[4];
    #pragma unroll
    for (int ni = 0; ni < 4; ++ni) {
        int h = w * 64 + ni * 16 + l15;
        vv[ni] = v[h];
        bb[ni] = bias[b * HH + h];
    }
    #pragma unroll
    for (int mi = 0; mi < 4; ++mi) {
        #pragma unroll
        for (int r = 0; r < 4; ++r) {
            float e = 0.f;
            #pragma unroll
            for (int ni = 0; ni < 4; ++ni) {
                float x = acc[mi][ni][r] + bb[ni];
                e += fmaxf(x, 0.f) * vv[ni];
            }
            e += __shfl_xor(e, 1);
            e += __shfl_xor(e, 2);
            e += __shfl_xor(e, 4);
            e += __shfl_xor(e, 8);
            if (l15 == 0) epart[w * BT + mi * 16 + quad * 4 + r] = e;
        }
    }
    __syncthreads();

    // block softmax (local m,l) by wave 0
    if (tid < 64) {
        float e = epart[0 * BT + tid] + epart[1 * BT + tid] + epart[2 * BT + tid] + epart[3 * BT + tid];
        float m = e;
        #pragma unroll
        for (int off = 32; off; off >>= 1) m = fmaxf(m, __shfl_xor(m, off));
        float p = __expf(e - m);
        float l = p;
        #pragma unroll
        for (int off = 32; off; off >>= 1) l += __shfl_xor(l, off);
        pbuf[tid] = p;
        if (tid == 0) { partM[pi] = m; partL[pi] = l; }
    }
    __syncthreads();

    // phase 3: partial context from LDS (bf16 tile) — no HBM re-read
    const int c4 = tid * 4;
    float o0 = 0.f, o1 = 0.f, o2 = 0.f, o3 = 0.f;
    #pragma unroll 8
    for (int t = 0; t < BT; ++t) {
        float p = pbuf[t];
        ushort4 e4 = *(const ushort4*)&As[t * LDA + c4];
        o0 += p * bf2f(e4.x);
        o1 += p * bf2f(e4.y);
        o2 += p * bf2f(e4.z);
        o3 += p * bf2f(e4.w);
    }
    float4 r4; r4.x = o0; r4.y = o1; r4.z = o2; r4.w = o3;
    *(float4*)(partO + (size_t)pi * CTXD + c4) = r4;
}

// ---- combine: per batch merge 64 (o,m,l) partials ----
__global__ void combine_kernel(const float* __restrict__ partO, const float* __restrict__ partM,
                               const float* __restrict__ partL, float* __restrict__ out) {
    __shared__ float sc[NTILES];
    __shared__ float sL;
    int b = blockIdx.x, tid = threadIdx.x;
    if (tid < 64) {
        float m = partM[b * NTILES + tid];
        float l = partL[b * NTILES + tid];
        float M = m;
        #pragma unroll
        for (int off = 32; off; off >>= 1) M = fmaxf(M, __shfl_xor(M, off));
        float s = __expf(m - M);
        sc[tid] = s;
        float Lp = l * s;
        #pragma unroll
        for (int off = 32; off; off >>= 1) Lp += __shfl_xor(Lp, off);
        if (tid == 0) sL = Lp;
    }
    __syncthreads();
    float4 o = {0.f, 0.f, 0.f, 0.f};
    const float* base = partO + (size_t)b * NTILES * CTXD;
    #pragma unroll 4
    for (int i = 0; i < NTILES; ++i) {
        float s = sc[i];
        float4 p4 = *(const float4*)(base + (size_t)i * CTXD + tid * 4);
        o.x += s * p4.x; o.y += s * p4.y; o.z += s * p4.z; o.w += s * p4.w;
    }
    float inv = 1.0f / sL;
    float4 r; r.x = o.x * inv; r.y = o.y * inv; r.z = o.z * inv; r.w = o.w * inv;
    ((float4*)out)[b * (CTXD / 4) + tid] = r;
}

extern "C" void kernel_launch(void* const* d_in, const int* in_sizes, int n_in,
                              void* d_out, int out_size, void* d_ws, size_t ws_size,
                              hipStream_t stream) {
    const float* prev  = (const float*)d_in[2];   // [32,1,512]
    const float* enc   = (const float*)d_in[3];   // [32,4096,1024]
    const float* Ww    = (const float*)d_in[4];   // [256,512]
    const float* Wb    = (const float*)d_in[5];   // [256]
    const float* Uw    = (const float*)d_in[6];   // [256,1024]
    const float* Ubias = (const float*)d_in[7];   // [256]
    const float* v     = (const float*)d_in[8];   // [256]
    float* out = (float*)d_out;                   // [32,1024]

    char* ws = (char*)d_ws;
    float* bias          = (float*)ws;                          // 32 KB
    unsigned short* Ub   = (unsigned short*)(ws + 32768);       // 512 KB
    float* partO         = (float*)(ws + 32768 + 524288);       // 8 MB
    float* partM         = partO + (size_t)BB * NTILES * CTXD;  // 8 KB
    float* partL         = partM + BB * NTILES;                 // 8 KB

    // allow >64 KB dynamic LDS (153,856 B) — idempotent, graph-capture-safe
    static int lds_set = 0;
    hipFuncSetAttribute((const void*)attn_main,
                        hipFuncAttributeMaxDynamicSharedMemorySize, SMEM_BYTES);
    (void)lds_set;

    uconv_kernel<<<dim3(256), dim3(256), 0, stream>>>(Uw, Ub);
    bias_kernel<<<dim3(BB), dim3(HH), 0, stream>>>(prev, Ww, Wb, Ubias, bias);
    attn_main<<<dim3(BB * NTILES), dim3(256), SMEM_BYTES, stream>>>(enc, Ub, bias, v, partO, partM, partL);
    combine_kernel<<<dim3(BB), dim3(256), 0, stream>>>(partO, partM, partL, out);
}